// Round 3
// baseline (290.520 us; speedup 1.0000x reference)
//
#include <hip/hip_runtime.h>
#include <cstdint>
#include <cstddef>

// ---- constants from the reference config (exact fp32 images of the Python doubles) ----
#define C_DECAY 0.99f   // (1.0 - alpha), alpha = 1.0/100.0
#define C_ALPHA 0.01f   // alpha
#define C_THR   0.58f   // IGNITE_THR
#define C_WTA   0.85f   // WTA_INH

#define NPB   32        // neurons per phase1-role block
#define TILE  256       // timesteps per LDS tile (phase1)
#define PADW  36        // padded row stride in floats (32 data + 4 pad): conflict-free col reads
#define BDIM  1024      // uniform block size for the fused kernel

// exact replica of the reference op order (no FMA contraction)
#define EMA_STEP(x) nmda = __fadd_rn(__fmul_rn(C_DECAY, nmda), __fmul_rn(C_ALPHA, (x)))

struct P2Lds {
  float ws1[16][16]; int wi1[16][16];
  float ws2[16][16]; int wi2[16][16];
  float wmx[16][16];
  int gj1[16], gj2[16];
};

// lexicographic merge of two (score desc, index asc) top-2 tuples
__device__ __forceinline__ void merge2(float& a1, int& i1, float& a2, int& i2,
                                       float b1, int j1, float b2, int j2) {
  const bool afirst = (a1 > b1) || (a1 == b1 && i1 < j1);
  const float w1 = afirst ? a1 : b1; const int wi1 = afirst ? i1 : j1;
  const float l1 = afirst ? b1 : a1; const int li1 = afirst ? j1 : i1;
  const float cc = afirst ? a2 : b2; const int ci  = afirst ? i2 : j2;
  const bool sfirst = (cc > l1) || (cc == l1 && ci < li1);
  a1 = w1; i1 = wi1;
  a2 = sfirst ? cc : l1; i2 = sfirst ? ci : li1;
}

// Fused stage kernel.
//  blocks [0, p1nb)        : phase1 (exact EMA chains) on steps [t0, t0+Tq)
//  blocks [p1nb, p1nb+nc2) : phase2 (top-2 + outputs) on chunks [c0, c0+nc2)
// Phase2 consumes bnd written by the PREVIOUS launch (kernel-boundary coherence).
__global__ __launch_bounds__(1024)
void gw_fused(const float* __restrict__ spikes, const float* __restrict__ nmda0,
              float* __restrict__ bnd, float* __restrict__ nst,
              float* __restrict__ mask, float* __restrict__ cov, float* __restrict__ nmf,
              int N, int Ls,
              int p1nb, int t0, int Tq, int firstq, int lastq,
              int c0, int nc2, float covval) {
  __shared__ float sb[2][TILE * PADW];   // 72 KiB; phase2 overlays a small struct on it
  const int N4 = N >> 2;
  const float4* sp4 = (const float4*)spikes;

  if ((int)blockIdx.x < p1nb) {
    // ------------------------- phase 1 role -------------------------
    const int w    = threadIdx.x >> 6;
    const int lane = threadIdx.x & 63;
    const int ntiles = Tq / TILE;
    if (w > 8) {                    // idle waves: matching barrier count, then exit
      for (int i = 0; i <= ntiles; ++i) __syncthreads();
      return;
    }
    const int n0 = blockIdx.x * NPB;
    const int lrow = lane >> 3;     // 8 rows per load round
    const int lc4  = lane & 7;      // float4 column
    const int cl   = lane & (NPB - 1);

    if (w >= 1) {                   // 8 loader waves: wave wl stages rows [(wl-1)*32, wl*32)
      const int r0 = (w - 1) * 32;
#pragma unroll
      for (int rnd = 0; rnd < 4; ++rnd) {
        const int row = r0 + rnd * 8 + lrow;
        float4 v = sp4[(size_t)(t0 + row) * N4 + (n0 >> 2) + lc4];
        *(float4*)&sb[0][row * PADW + lc4 * 4] = v;
      }
    }
    __syncthreads();

    float nmda = 0.0f;
    if (w == 0) nmda = firstq ? nmda0[n0 + cl] : nst[n0 + cl];
    const int Lm1 = (1 << Ls) - 1;

    for (int tile = 0; tile < ntiles; ++tile) {
      const int cur = tile & 1;
      if (w == 0) {
        const float* buf = sb[cur];
        const int tb0 = t0 + tile * TILE;
        float tA[16], tB[16];
#pragma unroll
        for (int i = 0; i < 16; ++i) tA[i] = buf[i * PADW + cl];
#pragma unroll
        for (int jp = 0; jp < TILE / 32; ++jp) {
          // even group j=2*jp: consume tA, prefetch group 2*jp+1 into tB
#pragma unroll
          for (int i = 0; i < 16; ++i) tB[i] = buf[((2 * jp + 1) * 16 + i) * PADW + cl];
          {
            const int tb = tb0 + (2 * jp) * 16;
            if ((tb & Lm1) == 0 && lane < NPB) bnd[(size_t)(tb >> Ls) * N + n0 + cl] = nmda;
          }
#pragma unroll
          for (int i = 0; i < 16; ++i) EMA_STEP(tA[i]);
          // odd group j=2*jp+1: consume tB, prefetch group 2*jp+2 into tA
          if (jp < TILE / 32 - 1) {
#pragma unroll
            for (int i = 0; i < 16; ++i) tA[i] = buf[((2 * jp + 2) * 16 + i) * PADW + cl];
          }
          {
            const int tb = tb0 + (2 * jp + 1) * 16;
            if ((tb & Lm1) == 0 && lane < NPB) bnd[(size_t)(tb >> Ls) * N + n0 + cl] = nmda;
          }
#pragma unroll
          for (int i = 0; i < 16; ++i) EMA_STEP(tB[i]);
        }
      } else {
        if (tile + 1 < ntiles) {
          const int tb0 = t0 + (tile + 1) * TILE;
          const int r0 = (w - 1) * 32;
#pragma unroll
          for (int rnd = 0; rnd < 4; ++rnd) {
            const int row = r0 + rnd * 8 + lrow;
            float4 v = sp4[(size_t)(tb0 + row) * N4 + (n0 >> 2) + lc4];
            *(float4*)&sb[cur ^ 1][row * PADW + lc4 * 4] = v;
          }
        }
      }
      __syncthreads();
    }
    if (w == 0 && lane < NPB) {
      nst[n0 + cl] = nmda;
      if (lastq) nmf[n0 + cl] = nmda;
    }
    return;
  }

  if ((int)blockIdx.x >= p1nb + nc2) return;

  // ------------------------- phase 2 role -------------------------
  P2Lds* p2 = (P2Lds*)&sb[0][0];
  const int tid  = threadIdx.x;            // [0, N/4)
  const int lane = tid & 63;
  const int wv   = tid >> 6;               // wave id [0,16)
  const int chunk = c0 + ((int)blockIdx.x - p1nb);
  const int L    = 1 << Ls;
  float4* mk4 = (float4*)mask;

  float4 nm = ((const float4*)bnd)[(size_t)chunk * N4 + tid];   // exact state before chunk
  const int base = tid * 4;
  const int t00  = chunk * L;

  for (int g = 0; g < L; g += 16) {
    const int tg = t00 + g;

    // ---------- pass A: 16 rows of EMA + per-wave stable top-2 ----------
#pragma unroll
    for (int r = 0; r < 16; ++r) {
      const float4 s = sp4[(size_t)(tg + r) * N4 + tid];

      nm.x = __fadd_rn(__fmul_rn(C_DECAY, nm.x), __fmul_rn(C_ALPHA, s.x));
      nm.y = __fadd_rn(__fmul_rn(C_DECAY, nm.y), __fmul_rn(C_ALPHA, s.y));
      nm.z = __fadd_rn(__fmul_rn(C_DECAY, nm.z), __fmul_rn(C_ALPHA, s.z));
      nm.w = __fadd_rn(__fmul_rn(C_DECAY, nm.w), __fmul_rn(C_ALPHA, s.w));

      const float c0s = __fmul_rn(nm.x, C_WTA);
      const float c1s = __fmul_rn(nm.y, C_WTA);
      const float c2s = __fmul_rn(nm.z, C_WTA);
      const float c3s = __fmul_rn(nm.w, C_WTA);

      float mx = fmaxf(fmaxf(nm.x, nm.y), fmaxf(nm.z, nm.w));

      // local stable top-2 (lowest index wins ties, like lax.top_k)
      float a1 = c0s; int i1 = base;
      float a2 = -__builtin_inff(); int i2 = 0x7fffffff;
      if (c1s > a1) { a2 = a1; i2 = i1; a1 = c1s; i1 = base + 1; }
      else if (c1s > a2) { a2 = c1s; i2 = base + 1; }
      if (c2s > a1) { a2 = a1; i2 = i1; a1 = c2s; i1 = base + 2; }
      else if (c2s > a2) { a2 = c2s; i2 = base + 2; }
      if (c3s > a1) { a2 = a1; i2 = i1; a1 = c3s; i1 = base + 3; }
      else if (c3s > a2) { a2 = c3s; i2 = base + 3; }

      // wave butterfly (64 lanes)
#pragma unroll
      for (int m = 1; m < 64; m <<= 1) {
        const float b1 = __shfl_xor(a1, m, 64); const int j1 = __shfl_xor(i1, m, 64);
        const float b2 = __shfl_xor(a2, m, 64); const int j2 = __shfl_xor(i2, m, 64);
        mx = fmaxf(mx, __shfl_xor(mx, m, 64));
        merge2(a1, i1, a2, i2, b1, j1, b2, j2);
      }
      if (lane == 0) {
        p2->ws1[r][wv] = a1; p2->wi1[r][wv] = i1;
        p2->ws2[r][wv] = a2; p2->wi2[r][wv] = i2;
        p2->wmx[r][wv] = mx;
      }
    }
    __syncthreads();

    // ---------- pass B: cross-wave reduce, 4 waves x 4 rows (16-lane groups) ----------
    if (wv < 4) {
      const int row = wv * 4 + (lane >> 4);
      const int q = lane & 15;
      float a1 = p2->ws1[row][q]; int i1 = p2->wi1[row][q];
      float a2 = p2->ws2[row][q]; int i2 = p2->wi2[row][q];
      float gm = p2->wmx[row][q];
#pragma unroll
      for (int m = 1; m < 16; m <<= 1) {
        const float b1 = __shfl_xor(a1, m, 64); const int j1 = __shfl_xor(i1, m, 64);
        const float b2 = __shfl_xor(a2, m, 64); const int j2 = __shfl_xor(i2, m, 64);
        gm = fmaxf(gm, __shfl_xor(gm, m, 64));
        merge2(a1, i1, a2, i2, b1, j1, b2, j2);
      }
      if ((lane & 15) == 0) {
        const int ig = (gm >= C_THR) ? 1 : 0;
        p2->gj1[row] = ig ? i1 : -1;     // -1 sentinel: nothing matches -> zero row
        p2->gj2[row] = ig ? i2 : -1;
        cov[tg + row] = ig ? covval : 0.0f;
      }
    }
    __syncthreads();

    // ---------- pass C: stream out 16 mask rows ----------
#pragma unroll
    for (int r = 0; r < 16; ++r) {
      const int j1 = p2->gj1[r], j2 = p2->gj2[r];
      float4 v;
      v.x = (j1 == base     || j2 == base)     ? 1.0f : 0.0f;
      v.y = (j1 == base + 1 || j2 == base + 1) ? 1.0f : 0.0f;
      v.z = (j1 == base + 2 || j2 == base + 2) ? 1.0f : 0.0f;
      v.w = (j1 == base + 3 || j2 == base + 3) ? 1.0f : 0.0f;
      mk4[(size_t)(tg + r) * N4 + tid] = v;
    }
    if (g + 16 < L) __syncthreads();   // protect LDS reuse across groups
  }
}

extern "C" void kernel_launch(void* const* d_in, const int* in_sizes, int n_in,
                              void* d_out, int out_size, void* d_ws, size_t ws_size,
                              hipStream_t stream) {
  const float* spikes = (const float*)d_in[0];
  const float* nmda0  = (const float*)d_in[1];
  const int N = in_sizes[1];
  const int T = in_sizes[0] / N;

  float* out  = (float*)d_out;
  float* mask = out;                               // [T, N]
  float* cov  = out + (size_t)T * N;               // [T]
  float* nmf  = cov + T;                           // [N]

  // boundary-state chunk length L = 1<<Ls; shrink boundary count if ws is small
  int Ls = 4;
  while (((size_t)(T >> Ls)) * (size_t)N * sizeof(float) + (size_t)N * sizeof(float) > ws_size
         && Ls < 13) ++Ls;
  const int C = T >> Ls;
  float* bnd = (float*)d_ws;                       // [C, N]
  float* nst = bnd + (size_t)C * N;                // [N] phase1 carry state between stages

  const int P1NB = N / NPB;                        // 128 phase1-role blocks
  const float covval = 2.0f / (float)N;

  // pipeline stages: Q quarters; Tq must be a multiple of TILE and of L
  int Q = 8;
  if (T % (Q * TILE) != 0 || (T / Q) % (1 << Ls) != 0) Q = 1;
  const int Tq  = T / Q;
  const int NB2 = Tq >> Ls;                        // phase2 chunks per stage

  for (int q = 0; q < Q; ++q) {
    const int nc2 = (q > 0) ? NB2 : 0;
    const int c0  = (q > 0) ? (q - 1) * NB2 : 0;
    gw_fused<<<P1NB + nc2, BDIM, 0, stream>>>(spikes, nmda0, bnd, nst, mask, cov, nmf,
                                              N, Ls, P1NB, q * Tq, Tq,
                                              (q == 0) ? 1 : 0, (q == Q - 1) ? 1 : 0,
                                              c0, nc2, covval);
  }
  // final stage: phase2 on the last quarter
  gw_fused<<<NB2, BDIM, 0, stream>>>(spikes, nmda0, bnd, nst, mask, cov, nmf,
                                     N, Ls, /*p1nb=*/0, 0, Tq, 0, 0,
                                     (Q - 1) * NB2, NB2, covval);
}

// Round 4
// 150.623 us; speedup vs baseline: 1.9288x; 1.9288x over previous
//
#include <hip/hip_runtime.h>
#include <cstdint>
#include <cstddef>

// ---- constants from the reference config (exact fp32 images of the Python doubles) ----
#define C_DECAY 0.99f   // (1.0 - alpha), alpha = 1.0/100.0
#define C_ALPHA 0.01f   // alpha
#define C_THR   0.58f   // IGNITE_THR
#define C_WTA   0.85f   // WTA_INH

#define NPB   16        // neurons per phase1 block (64B per spike row slice)
#define TILE  256       // timesteps per LDS tile (phase1); 16 KiB per buffer

// exact replica of the reference op order (no FMA contraction)
#define EMA_STEP(x) nmda = __fadd_rn(__fmul_rn(C_DECAY, nmda), __fmul_rn(C_ALPHA, (x)))

typedef const __attribute__((address_space(1))) void g_void;
typedef __attribute__((address_space(3))) void l_void;

// async global->LDS DMA, 16B/lane, wave-uniform LDS base (lane i lands at base + i*16)
__device__ __forceinline__ void gload_lds16(const float* g, float* l) {
  __builtin_amdgcn_global_load_lds((g_void*)g, (l_void*)l, 16, 0, 0);
}

// ---------------- Phase 1: exact EMA chains, boundary states every L steps ----------------
// grid: N/16 = 256 blocks; block: 128 threads (wave0 = compute, wave1 = async loader)
__global__ __launch_bounds__(128)
void gw_phase1(const float* __restrict__ spikes, const float* __restrict__ nmda0,
               float* __restrict__ bnd, float* __restrict__ nmf,
               int T, int N, int Ls) {
  __shared__ float sb[2][TILE * NPB];   // 2 x 16 KiB, linear [step][neuron]
  const int w    = threadIdx.x >> 6;
  const int lane = threadIdx.x & 63;
  const int nblk = gridDim.x;                       // N/NPB
  // XCD-contiguous column mapping: blocks on one XCD cover adjacent neuron slices
  const int bs   = (nblk % 8 == 0) ? ((blockIdx.x & 7) * (nblk >> 3) + (blockIdx.x >> 3))
                                   : (int)blockIdx.x;
  const int n0   = bs * NPB;
  const int ntiles = T / TILE;
  const int Lm1  = (1 << Ls) - 1;
  const int grow = lane >> 2;        // row within a 16-row DMA group
  const int gc   = (lane & 3) * 4;   // float column within the 16-float row

  if (w == 1) {   // prologue: stage tile 0 (16 x 1KiB async DMAs)
#pragma unroll
    for (int j = 0; j < TILE / 16; ++j)
      gload_lds16(spikes + (size_t)(j * 16 + grow) * N + n0 + gc, &sb[0][j * 256]);
  }
  __syncthreads();   // drains vmcnt -> tile 0 resident

  const int nn = lane & (NPB - 1);   // 4 lanes duplicate each neuron (broadcast reads)
  float nmda = 0.0f;
  if (w == 0) nmda = nmda0[n0 + nn];

  for (int tile = 0; tile < ntiles; ++tile) {
    const int cur = tile & 1;
    if (w == 0) {
      const float* buf = sb[cur];
      const int t0 = tile * TILE;
      float tA[16], tB[16];
#pragma unroll
      for (int i = 0; i < 16; ++i) tA[i] = buf[i * NPB + nn];
#pragma unroll
      for (int jp = 0; jp < TILE / 32; ++jp) {
        // even group: consume tA, prefetch odd group into tB
#pragma unroll
        for (int i = 0; i < 16; ++i) tB[i] = buf[((2 * jp + 1) * 16 + i) * NPB + nn];
        { const int tb = t0 + 2 * jp * 16;
          if ((tb & Lm1) == 0 && lane < NPB) bnd[(size_t)(tb >> Ls) * N + n0 + lane] = nmda; }
#pragma unroll
        for (int i = 0; i < 16; ++i) EMA_STEP(tA[i]);
        // odd group: consume tB, prefetch next even group into tA
        if (jp < TILE / 32 - 1) {
#pragma unroll
          for (int i = 0; i < 16; ++i) tA[i] = buf[((2 * jp + 2) * 16 + i) * NPB + nn];
        }
        { const int tb = t0 + (2 * jp + 1) * 16;
          if ((tb & Lm1) == 0 && lane < NPB) bnd[(size_t)(tb >> Ls) * N + n0 + lane] = nmda; }
#pragma unroll
        for (int i = 0; i < 16; ++i) EMA_STEP(tB[i]);
      }
    } else if (tile + 1 < ntiles) {
      const int t0 = (tile + 1) * TILE;
#pragma unroll
      for (int j = 0; j < TILE / 16; ++j)
        gload_lds16(spikes + (size_t)(t0 + j * 16 + grow) * N + n0 + gc, &sb[cur ^ 1][j * 256]);
    }
    __syncthreads();   // compiler-inserted vmcnt(0) drain completes the async DMAs
  }
  if (w == 0 && lane < NPB) nmf[n0 + lane] = nmda;
}

// lexicographic merge of two (score desc, index asc) top-2 tuples
__device__ __forceinline__ void merge2(float& a1, int& i1, float& a2, int& i2,
                                       float b1, int j1, float b2, int j2) {
  const bool afirst = (a1 > b1) || (a1 == b1 && i1 < j1);
  const float w1 = afirst ? a1 : b1; const int wi1 = afirst ? i1 : j1;
  const float l1 = afirst ? b1 : a1; const int li1 = afirst ? j1 : i1;
  const float cc = afirst ? a2 : b2; const int ci  = afirst ? i2 : j2;
  const bool sfirst = (cc > l1) || (cc == l1 && ci < li1);
  a1 = w1; i1 = wi1;
  a2 = sfirst ? cc : l1; i2 = sfirst ? ci : li1;
}

// ---------------- Phase 2: recompute rows from exact boundary, stable top-2, write outputs ----------------
// grid: C = T/L blocks; block: N/4 = 1024 threads (16 waves). 8-row register batches.
__global__ __launch_bounds__(1024)
void gw_phase2(const float* __restrict__ spikes, const float* __restrict__ bnd,
               float* __restrict__ mask, float* __restrict__ cov,
               int T, int N, int L, float covval) {
  const int tid  = threadIdx.x;            // [0, N/4)
  const int lane = tid & 63;
  const int wv   = tid >> 6;               // wave id [0,16)
  const int N4   = N >> 2;
  const float4* sp4 = (const float4*)spikes;
  float4* mk4 = (float4*)mask;

  __shared__ float ws1[8][16]; __shared__ int wi1s[8][16];
  __shared__ float ws2[8][16]; __shared__ int wi2s[8][16];
  __shared__ float wmx[8][16];
  __shared__ int gj1[8], gj2[8];

  float4 nm = ((const float4*)bnd)[(size_t)blockIdx.x * N4 + tid];   // exact state before chunk
  const int base = tid * 4;
  const int t00  = blockIdx.x * L;

  for (int g = 0; g < L; g += 8) {
    const int tg = t00 + g;

    // batch-load 8 spike rows into registers (independent -> one latency exposure)
    float4 sr[8];
#pragma unroll
    for (int r = 0; r < 8; ++r) sr[r] = sp4[(size_t)(tg + r) * N4 + tid];

    // ---------- pass A: 8 rows of EMA + per-wave stable top-2 ----------
#pragma unroll
    for (int r = 0; r < 8; ++r) {
      const float4 s = sr[r];

      nm.x = __fadd_rn(__fmul_rn(C_DECAY, nm.x), __fmul_rn(C_ALPHA, s.x));
      nm.y = __fadd_rn(__fmul_rn(C_DECAY, nm.y), __fmul_rn(C_ALPHA, s.y));
      nm.z = __fadd_rn(__fmul_rn(C_DECAY, nm.z), __fmul_rn(C_ALPHA, s.z));
      nm.w = __fadd_rn(__fmul_rn(C_DECAY, nm.w), __fmul_rn(C_ALPHA, s.w));

      const float c0s = __fmul_rn(nm.x, C_WTA);
      const float c1s = __fmul_rn(nm.y, C_WTA);
      const float c2s = __fmul_rn(nm.z, C_WTA);
      const float c3s = __fmul_rn(nm.w, C_WTA);

      float mx = fmaxf(fmaxf(nm.x, nm.y), fmaxf(nm.z, nm.w));

      // local stable top-2 (lowest index wins ties, like lax.top_k)
      float a1 = c0s; int i1 = base;
      float a2 = -__builtin_inff(); int i2 = 0x7fffffff;
      if (c1s > a1) { a2 = a1; i2 = i1; a1 = c1s; i1 = base + 1; }
      else if (c1s > a2) { a2 = c1s; i2 = base + 1; }
      if (c2s > a1) { a2 = a1; i2 = i1; a1 = c2s; i1 = base + 2; }
      else if (c2s > a2) { a2 = c2s; i2 = base + 2; }
      if (c3s > a1) { a2 = a1; i2 = i1; a1 = c3s; i1 = base + 3; }
      else if (c3s > a2) { a2 = c3s; i2 = base + 3; }

      // wave butterfly (64 lanes)
#pragma unroll
      for (int m = 1; m < 64; m <<= 1) {
        const float b1 = __shfl_xor(a1, m, 64); const int j1 = __shfl_xor(i1, m, 64);
        const float b2 = __shfl_xor(a2, m, 64); const int j2 = __shfl_xor(i2, m, 64);
        mx = fmaxf(mx, __shfl_xor(mx, m, 64));
        merge2(a1, i1, a2, i2, b1, j1, b2, j2);
      }
      if (lane == 0) { ws1[r][wv] = a1; wi1s[r][wv] = i1; ws2[r][wv] = a2; wi2s[r][wv] = i2; wmx[r][wv] = mx; }
    }
    __syncthreads();

    // ---------- pass B: cross-wave reduce, 2 waves x 4 rows (16-lane groups) ----------
    if (wv < 2) {
      const int row = wv * 4 + (lane >> 4);
      const int q = lane & 15;
      float a1 = ws1[row][q]; int i1 = wi1s[row][q];
      float a2 = ws2[row][q]; int i2 = wi2s[row][q];
      float gm = wmx[row][q];
#pragma unroll
      for (int m = 1; m < 16; m <<= 1) {
        const float b1 = __shfl_xor(a1, m, 64); const int j1 = __shfl_xor(i1, m, 64);
        const float b2 = __shfl_xor(a2, m, 64); const int j2 = __shfl_xor(i2, m, 64);
        gm = fmaxf(gm, __shfl_xor(gm, m, 64));
        merge2(a1, i1, a2, i2, b1, j1, b2, j2);
      }
      if ((lane & 15) == 0) {
        const int ig = (gm >= C_THR) ? 1 : 0;
        gj1[row] = ig ? i1 : -1;        // -1 sentinel: nothing matches -> zero row
        gj2[row] = ig ? i2 : -1;
        cov[tg + row] = ig ? covval : 0.0f;
      }
    }
    __syncthreads();

    // ---------- pass C: stream out 8 mask rows ----------
#pragma unroll
    for (int r = 0; r < 8; ++r) {
      const int j1 = gj1[r], j2 = gj2[r];
      float4 v;
      v.x = (j1 == base     || j2 == base)     ? 1.0f : 0.0f;
      v.y = (j1 == base + 1 || j2 == base + 1) ? 1.0f : 0.0f;
      v.z = (j1 == base + 2 || j2 == base + 2) ? 1.0f : 0.0f;
      v.w = (j1 == base + 3 || j2 == base + 3) ? 1.0f : 0.0f;
      mk4[(size_t)(tg + r) * N4 + tid] = v;
    }
    if (g + 8 < L) __syncthreads();   // protect LDS reuse across groups
  }
}

extern "C" void kernel_launch(void* const* d_in, const int* in_sizes, int n_in,
                              void* d_out, int out_size, void* d_ws, size_t ws_size,
                              hipStream_t stream) {
  const float* spikes = (const float*)d_in[0];
  const float* nmda0  = (const float*)d_in[1];
  const int N = in_sizes[1];
  const int T = in_sizes[0] / N;

  float* out  = (float*)d_out;
  float* mask = out;                               // [T, N]
  float* cov  = out + (size_t)T * N;               // [T]
  float* nmf  = cov + T;                           // [N]

  // boundary-state chunk length L = 1<<Ls; shrink boundary count if ws is small
  int Ls = 4;
  while (((size_t)(T >> Ls)) * (size_t)N * sizeof(float) > ws_size && Ls < 13) ++Ls;
  const int L = 1 << Ls;
  const int C = T >> Ls;
  float* bnd = (float*)d_ws;                       // [C, N]

  gw_phase1<<<N / NPB, 128, 0, stream>>>(spikes, nmda0, bnd, nmf, T, N, Ls);
  gw_phase2<<<C, N / 4, 0, stream>>>(spikes, bnd, mask, cov, T, N, L, 2.0f / (float)N);
}

// Round 6
// 138.155 us; speedup vs baseline: 2.1029x; 1.0902x over previous
//
#include <hip/hip_runtime.h>
#include <cstdint>
#include <cstddef>

// ---- constants from the reference config (exact fp32 images of the Python doubles) ----
#define C_DECAY 0.99f   // (1.0 - alpha), alpha = 1.0/100.0
#define C_ALPHA 0.01f   // alpha
#define C_THR   0.58f   // IGNITE_THR
#define C_WTA   0.85f   // WTA_INH

#define NPB   16        // neurons per phase1 block (64B per spike row slice)
#define TILE  256       // timesteps per LDS tile (phase1); 16 KiB per buffer

// exact replica of the reference op order (no FMA contraction)
#define EMA_STEP(x) nmda = __fadd_rn(__fmul_rn(C_DECAY, nmda), __fmul_rn(C_ALPHA, (x)))

typedef const __attribute__((address_space(1))) void g_void;
typedef __attribute__((address_space(3))) void l_void;

// async global->LDS DMA, 16B/lane, wave-uniform LDS base (lane i lands at base + i*16)
__device__ __forceinline__ void gload_lds16(const float* g, float* l) {
  __builtin_amdgcn_global_load_lds((g_void*)g, (l_void*)l, 16, 0, 0);
}

// ---------------- Phase 1: exact EMA chains, boundary states every L steps ----------------
// grid: N/16 = 256 blocks; block: 128 threads (wave0 = compute, wave1 = async loader)
// [PROVEN in R4: passed, ~62us]
__global__ __launch_bounds__(128)
void gw_phase1(const float* __restrict__ spikes, const float* __restrict__ nmda0,
               float* __restrict__ bnd, float* __restrict__ nmf,
               int T, int N, int Ls) {
  __shared__ float sb[2][TILE * NPB];   // 2 x 16 KiB, linear [step][neuron]
  const int w    = threadIdx.x >> 6;
  const int lane = threadIdx.x & 63;
  const int nblk = gridDim.x;                       // N/NPB
  // XCD-contiguous column mapping: blocks on one XCD cover adjacent neuron slices
  const int bs   = (nblk % 8 == 0) ? ((blockIdx.x & 7) * (nblk >> 3) + (blockIdx.x >> 3))
                                   : (int)blockIdx.x;
  const int n0   = bs * NPB;
  const int ntiles = T / TILE;
  const int Lm1  = (1 << Ls) - 1;
  const int grow = lane >> 2;        // row within a 16-row DMA group
  const int gc   = (lane & 3) * 4;   // float column within the 16-float row

  if (w == 1) {   // prologue: stage tile 0 (16 x 1KiB async DMAs)
#pragma unroll
    for (int j = 0; j < TILE / 16; ++j)
      gload_lds16(spikes + (size_t)(j * 16 + grow) * N + n0 + gc, &sb[0][j * 256]);
  }
  __syncthreads();   // drains vmcnt -> tile 0 resident

  const int nn = lane & (NPB - 1);   // 4 lanes duplicate each neuron (broadcast reads)
  float nmda = 0.0f;
  if (w == 0) nmda = nmda0[n0 + nn];

  for (int tile = 0; tile < ntiles; ++tile) {
    const int cur = tile & 1;
    if (w == 0) {
      const float* buf = sb[cur];
      const int t0 = tile * TILE;
      float tA[16], tB[16];
#pragma unroll
      for (int i = 0; i < 16; ++i) tA[i] = buf[i * NPB + nn];
#pragma unroll
      for (int jp = 0; jp < TILE / 32; ++jp) {
        // even group: consume tA, prefetch odd group into tB
#pragma unroll
        for (int i = 0; i < 16; ++i) tB[i] = buf[((2 * jp + 1) * 16 + i) * NPB + nn];
        { const int tb = t0 + 2 * jp * 16;
          if ((tb & Lm1) == 0 && lane < NPB) bnd[(size_t)(tb >> Ls) * N + n0 + lane] = nmda; }
#pragma unroll
        for (int i = 0; i < 16; ++i) EMA_STEP(tA[i]);
        // odd group: consume tB, prefetch next even group into tA
        if (jp < TILE / 32 - 1) {
#pragma unroll
          for (int i = 0; i < 16; ++i) tA[i] = buf[((2 * jp + 2) * 16 + i) * NPB + nn];
        }
        { const int tb = t0 + (2 * jp + 1) * 16;
          if ((tb & Lm1) == 0 && lane < NPB) bnd[(size_t)(tb >> Ls) * N + n0 + lane] = nmda; }
#pragma unroll
        for (int i = 0; i < 16; ++i) EMA_STEP(tB[i]);
      }
    } else if (tile + 1 < ntiles) {
      const int t0 = (tile + 1) * TILE;
#pragma unroll
      for (int j = 0; j < TILE / 16; ++j)
        gload_lds16(spikes + (size_t)(t0 + j * 16 + grow) * N + n0 + gc, &sb[cur ^ 1][j * 256]);
    }
    __syncthreads();   // compiler-inserted vmcnt(0) drain completes the async DMAs
  }
  if (w == 0 && lane < NPB) nmf[n0 + lane] = nmda;
}

// lexicographic merge of two (score desc, index asc) top-2 tuples
__device__ __forceinline__ void merge2(float& a1, int& i1, float& a2, int& i2,
                                       float b1, int j1, float b2, int j2) {
  const bool afirst = (a1 > b1) || (a1 == b1 && i1 < j1);
  const float w1 = afirst ? a1 : b1; const int wi1 = afirst ? i1 : j1;
  const float l1 = afirst ? b1 : a1; const int li1 = afirst ? j1 : i1;
  const float cc = afirst ? a2 : b2; const int ci  = afirst ? i2 : j2;
  const bool sfirst = (cc > l1) || (cc == l1 && ci < li1);
  a1 = w1; i1 = wi1;
  a2 = sfirst ? cc : l1; i2 = sfirst ? ci : li1;
}

// ---------------- Phase 2: R2 structure [PROVEN in R2: passed, ~45us] ----------------
// grid: C = T/L blocks; block: N/4 = 1024 threads (16 waves). 2 barriers per 16-row group.
__global__ __launch_bounds__(1024)
void gw_phase2(const float* __restrict__ spikes, const float* __restrict__ bnd,
               float* __restrict__ mask, float* __restrict__ cov,
               int T, int N, int L, float covval) {
  const int tid  = threadIdx.x;            // [0, N/4)
  const int lane = tid & 63;
  const int wv   = tid >> 6;               // wave id [0,16)
  const int N4   = N >> 2;
  const float4* sp4 = (const float4*)spikes;
  float4* mk4 = (float4*)mask;

  __shared__ float ws1[16][16]; __shared__ int wi1s[16][16];
  __shared__ float ws2[16][16]; __shared__ int wi2s[16][16];
  __shared__ float wmx[16][16];
  __shared__ int gj1[16], gj2[16];

  float4 nm = ((const float4*)bnd)[(size_t)blockIdx.x * N4 + tid];   // exact state before chunk
  const int base = tid * 4;
  const int t00  = blockIdx.x * L;

  for (int g = 0; g < L; g += 16) {
    const int tg = t00 + g;

    // ---------- pass A: 16 rows of EMA + per-wave stable top-2 ----------
#pragma unroll
    for (int r = 0; r < 16; ++r) {
      const float4 s = sp4[(size_t)(tg + r) * N4 + tid];

      nm.x = __fadd_rn(__fmul_rn(C_DECAY, nm.x), __fmul_rn(C_ALPHA, s.x));
      nm.y = __fadd_rn(__fmul_rn(C_DECAY, nm.y), __fmul_rn(C_ALPHA, s.y));
      nm.z = __fadd_rn(__fmul_rn(C_DECAY, nm.z), __fmul_rn(C_ALPHA, s.z));
      nm.w = __fadd_rn(__fmul_rn(C_DECAY, nm.w), __fmul_rn(C_ALPHA, s.w));

      const float c0s = __fmul_rn(nm.x, C_WTA);
      const float c1s = __fmul_rn(nm.y, C_WTA);
      const float c2s = __fmul_rn(nm.z, C_WTA);
      const float c3s = __fmul_rn(nm.w, C_WTA);

      float mx = fmaxf(fmaxf(nm.x, nm.y), fmaxf(nm.z, nm.w));

      // local stable top-2 (lowest index wins ties, like lax.top_k)
      float a1 = c0s; int i1 = base;
      float a2 = -__builtin_inff(); int i2 = 0x7fffffff;
      if (c1s > a1) { a2 = a1; i2 = i1; a1 = c1s; i1 = base + 1; }
      else if (c1s > a2) { a2 = c1s; i2 = base + 1; }
      if (c2s > a1) { a2 = a1; i2 = i1; a1 = c2s; i1 = base + 2; }
      else if (c2s > a2) { a2 = c2s; i2 = base + 2; }
      if (c3s > a1) { a2 = a1; i2 = i1; a1 = c3s; i1 = base + 3; }
      else if (c3s > a2) { a2 = c3s; i2 = base + 3; }

      // wave butterfly (64 lanes)
#pragma unroll
      for (int m = 1; m < 64; m <<= 1) {
        const float b1 = __shfl_xor(a1, m, 64); const int j1 = __shfl_xor(i1, m, 64);
        const float b2 = __shfl_xor(a2, m, 64); const int j2 = __shfl_xor(i2, m, 64);
        mx = fmaxf(mx, __shfl_xor(mx, m, 64));
        merge2(a1, i1, a2, i2, b1, j1, b2, j2);
      }
      if (lane == 0) { ws1[r][wv] = a1; wi1s[r][wv] = i1; ws2[r][wv] = a2; wi2s[r][wv] = i2; wmx[r][wv] = mx; }
    }
    __syncthreads();

    // ---------- pass B: cross-wave reduce, 4 waves x 4 rows (16-lane groups) ----------
    if (wv < 4) {
      const int row = wv * 4 + (lane >> 4);
      const int q = lane & 15;
      float a1 = ws1[row][q]; int i1 = wi1s[row][q];
      float a2 = ws2[row][q]; int i2 = wi2s[row][q];
      float gm = wmx[row][q];
#pragma unroll
      for (int m = 1; m < 16; m <<= 1) {
        const float b1 = __shfl_xor(a1, m, 64); const int j1 = __shfl_xor(i1, m, 64);
        const float b2 = __shfl_xor(a2, m, 64); const int j2 = __shfl_xor(i2, m, 64);
        gm = fmaxf(gm, __shfl_xor(gm, m, 64));
        merge2(a1, i1, a2, i2, b1, j1, b2, j2);
      }
      if ((lane & 15) == 0) {
        const int ig = (gm >= C_THR) ? 1 : 0;
        gj1[row] = ig ? i1 : -1;        // -1 sentinel: nothing matches -> zero row
        gj2[row] = ig ? i2 : -1;
        cov[tg + row] = ig ? covval : 0.0f;
      }
    }
    __syncthreads();

    // ---------- pass C: stream out 16 mask rows ----------
#pragma unroll
    for (int r = 0; r < 16; ++r) {
      const int j1 = gj1[r], j2 = gj2[r];
      float4 v;
      v.x = (j1 == base     || j2 == base)     ? 1.0f : 0.0f;
      v.y = (j1 == base + 1 || j2 == base + 1) ? 1.0f : 0.0f;
      v.z = (j1 == base + 2 || j2 == base + 2) ? 1.0f : 0.0f;
      v.w = (j1 == base + 3 || j2 == base + 3) ? 1.0f : 0.0f;
      mk4[(size_t)(tg + r) * N4 + tid] = v;
    }
    if (g + 16 < L) __syncthreads();   // protect LDS reuse across groups
  }
}

extern "C" void kernel_launch(void* const* d_in, const int* in_sizes, int n_in,
                              void* d_out, int out_size, void* d_ws, size_t ws_size,
                              hipStream_t stream) {
  const float* spikes = (const float*)d_in[0];
  const float* nmda0  = (const float*)d_in[1];
  const int N = in_sizes[1];
  const int T = in_sizes[0] / N;

  float* out  = (float*)d_out;
  float* mask = out;                               // [T, N]
  float* cov  = out + (size_t)T * N;               // [T]
  float* nmf  = cov + T;                           // [N]

  // boundary-state chunk length L = 1<<Ls; shrink boundary count if ws is small
  int Ls = 4;
  while (((size_t)(T >> Ls)) * (size_t)N * sizeof(float) > ws_size && Ls < 13) ++Ls;
  const int L = 1 << Ls;
  const int C = T >> Ls;
  float* bnd = (float*)d_ws;                       // [C, N]

  gw_phase1<<<N / NPB, 128, 0, stream>>>(spikes, nmda0, bnd, nmf, T, N, Ls);
  gw_phase2<<<C, N / 4, 0, stream>>>(spikes, bnd, mask, cov, T, N, L, 2.0f / (float)N);
}

// Round 7
// 116.971 us; speedup vs baseline: 2.4837x; 1.1811x over previous
//
#include <hip/hip_runtime.h>
#include <cstdint>
#include <cstddef>

// ---- constants from the reference config (exact fp32 images of the Python doubles) ----
#define C_DECAY 0.99f   // (1.0 - alpha), alpha = 1.0/100.0
#define C_ALPHA 0.01f   // alpha
#define C_THR   0.58f   // IGNITE_THR
#define C_WTA   0.85f   // WTA_INH

#define NPB   16        // neurons per phase1 block (64B per spike row slice)
#define TILE  256       // timesteps per LDS tile (phase1); 16 KiB per buffer

// exact replica of the reference op order (no FMA contraction)
#define EMA_STEP(x) nmda = __fadd_rn(__fmul_rn(C_DECAY, nmda), __fmul_rn(C_ALPHA, (x)))

typedef const __attribute__((address_space(1))) void g_void;
typedef __attribute__((address_space(3))) void l_void;
typedef float f32x4 __attribute__((ext_vector_type(4)));

// async global->LDS DMA, 16B/lane, wave-uniform LDS base (lane i lands at base + i*16)
__device__ __forceinline__ void gload_lds16(const float* g, float* l) {
  __builtin_amdgcn_global_load_lds((g_void*)g, (l_void*)l, 16, 0, 0);
}

// ---------------- Phase 1: exact EMA chains, boundary states every L steps ----------------
// [PROVEN R4/R6: passed, ~60us] grid: N/16 blocks; block: 128 (wave0 compute, wave1 async loader)
__global__ __launch_bounds__(128)
void gw_phase1(const float* __restrict__ spikes, const float* __restrict__ nmda0,
               float* __restrict__ bnd, float* __restrict__ nmf,
               int T, int N, int Ls) {
  __shared__ float sb[2][TILE * NPB];   // 2 x 16 KiB, linear [step][neuron]
  const int w    = threadIdx.x >> 6;
  const int lane = threadIdx.x & 63;
  const int nblk = gridDim.x;                       // N/NPB
  const int bs   = (nblk % 8 == 0) ? ((blockIdx.x & 7) * (nblk >> 3) + (blockIdx.x >> 3))
                                   : (int)blockIdx.x;
  const int n0   = bs * NPB;
  const int ntiles = T / TILE;
  const int Lm1  = (1 << Ls) - 1;
  const int grow = lane >> 2;        // row within a 16-row DMA group
  const int gc   = (lane & 3) * 4;   // float column within the 16-float row

  if (w == 1) {   // prologue: stage tile 0 (16 x 1KiB async DMAs)
#pragma unroll
    for (int j = 0; j < TILE / 16; ++j)
      gload_lds16(spikes + (size_t)(j * 16 + grow) * N + n0 + gc, &sb[0][j * 256]);
  }
  __syncthreads();   // drains vmcnt -> tile 0 resident

  const int nn = lane & (NPB - 1);   // 4 lanes duplicate each neuron (broadcast reads)
  float nmda = 0.0f;
  if (w == 0) nmda = nmda0[n0 + nn];

  for (int tile = 0; tile < ntiles; ++tile) {
    const int cur = tile & 1;
    if (w == 0) {
      const float* buf = sb[cur];
      const int t0 = tile * TILE;
      float tA[16], tB[16];
#pragma unroll
      for (int i = 0; i < 16; ++i) tA[i] = buf[i * NPB + nn];
#pragma unroll
      for (int jp = 0; jp < TILE / 32; ++jp) {
#pragma unroll
        for (int i = 0; i < 16; ++i) tB[i] = buf[((2 * jp + 1) * 16 + i) * NPB + nn];
        { const int tb = t0 + 2 * jp * 16;
          if ((tb & Lm1) == 0 && lane < NPB) bnd[(size_t)(tb >> Ls) * N + n0 + lane] = nmda; }
#pragma unroll
        for (int i = 0; i < 16; ++i) EMA_STEP(tA[i]);
        if (jp < TILE / 32 - 1) {
#pragma unroll
          for (int i = 0; i < 16; ++i) tA[i] = buf[((2 * jp + 2) * 16 + i) * NPB + nn];
        }
        { const int tb = t0 + (2 * jp + 1) * 16;
          if ((tb & Lm1) == 0 && lane < NPB) bnd[(size_t)(tb >> Ls) * N + n0 + lane] = nmda; }
#pragma unroll
        for (int i = 0; i < 16; ++i) EMA_STEP(tB[i]);
      }
    } else if (tile + 1 < ntiles) {
      const int t0 = (tile + 1) * TILE;
#pragma unroll
      for (int j = 0; j < TILE / 16; ++j)
        gload_lds16(spikes + (size_t)(t0 + j * 16 + grow) * N + n0 + gc, &sb[cur ^ 1][j * 256]);
    }
    __syncthreads();
  }
  if (w == 0 && lane < NPB) nmf[n0 + lane] = nmda;
}

// lexicographic merge of two (score desc, index asc) top-2 tuples
__device__ __forceinline__ void merge2(float& a1, int& i1, float& a2, int& i2,
                                       float b1, int j1, float b2, int j2) {
  const bool afirst = (a1 > b1) || (a1 == b1 && i1 < j1);
  const float w1 = afirst ? a1 : b1; const int wi1 = afirst ? i1 : j1;
  const float l1 = afirst ? b1 : a1; const int li1 = afirst ? j1 : i1;
  const float cc = afirst ? a2 : b2; const int ci  = afirst ? i2 : j2;
  const bool sfirst = (cc > l1) || (cc == l1 && ci < li1);
  a1 = w1; i1 = wi1;
  a2 = sfirst ? cc : l1; i2 = sfirst ? ci : li1;
}

// local stable top-2 update with a new (score, idx), idx processed in ascending order
#define LOCAL_TOP2(c, idx)                                         \
  if ((c) > a1) { a2 = a1; i2 = i1; a1 = (c); i1 = (idx); }        \
  else if ((c) > a2) { a2 = (c); i2 = (idx); }

// ---------------- Phase 2: 512 threads, 8 neurons/thread, ping-pong row prefetch ----------------
// grid: C = T/L blocks; block: 512 threads (8 waves). 2 barriers per 16-row group.
__global__ __launch_bounds__(512)
void gw_phase2(const float* __restrict__ spikes, const float* __restrict__ bnd,
               float* __restrict__ mask, float* __restrict__ cov,
               int T, int N, int L, float covval) {
  const int tid  = threadIdx.x;            // [0, 512)
  const int lane = tid & 63;
  const int wv   = tid >> 6;               // wave id [0,8)
  const int N4   = N >> 2;                 // 1024
  const int half = N4 >> 1;                // 512: float4 offset of second segment
  const float4* sp4 = (const float4*)spikes;
  f32x4* mk4 = (f32x4*)mask;

  __shared__ float ws1[16][8]; __shared__ int wi1s[16][8];
  __shared__ float ws2[16][8]; __shared__ int wi2s[16][8];
  __shared__ float wmx[16][8];
  __shared__ int gj1[16], gj2[16];

  // exact state before this chunk: two float4 segments per thread
  float4 nmA = ((const float4*)bnd)[(size_t)blockIdx.x * N4 + tid];
  float4 nmB = ((const float4*)bnd)[(size_t)blockIdx.x * N4 + tid + half];
  const int baseA = tid * 4;               // neurons [baseA, baseA+4)
  const int baseB = baseA + (N >> 1);      // neurons [baseB, baseB+4)
  const int t00   = blockIdx.x * L;

  for (int g = 0; g < L; g += 16) {
    const int tg = t00 + g;

    // ---------- pass A: 16 rows, ping-pong prefetched ----------
    float4 pA[2], pB[2];
    pA[0] = sp4[(size_t)tg * N4 + tid];
    pB[0] = sp4[(size_t)tg * N4 + tid + half];
#pragma unroll
    for (int r = 0; r < 16; ++r) {
      if (r < 15) {   // issue next row's loads before consuming current (hides latency)
        pA[(r + 1) & 1] = sp4[(size_t)(tg + r + 1) * N4 + tid];
        pB[(r + 1) & 1] = sp4[(size_t)(tg + r + 1) * N4 + tid + half];
      }
      const float4 s  = pA[r & 1];
      const float4 s2 = pB[r & 1];

      // exact EMA update (reference op order)
      nmA.x = __fadd_rn(__fmul_rn(C_DECAY, nmA.x), __fmul_rn(C_ALPHA, s.x));
      nmA.y = __fadd_rn(__fmul_rn(C_DECAY, nmA.y), __fmul_rn(C_ALPHA, s.y));
      nmA.z = __fadd_rn(__fmul_rn(C_DECAY, nmA.z), __fmul_rn(C_ALPHA, s.z));
      nmA.w = __fadd_rn(__fmul_rn(C_DECAY, nmA.w), __fmul_rn(C_ALPHA, s.w));
      nmB.x = __fadd_rn(__fmul_rn(C_DECAY, nmB.x), __fmul_rn(C_ALPHA, s2.x));
      nmB.y = __fadd_rn(__fmul_rn(C_DECAY, nmB.y), __fmul_rn(C_ALPHA, s2.y));
      nmB.z = __fadd_rn(__fmul_rn(C_DECAY, nmB.z), __fmul_rn(C_ALPHA, s2.z));
      nmB.w = __fadd_rn(__fmul_rn(C_DECAY, nmB.w), __fmul_rn(C_ALPHA, s2.w));

      // scores (reference compares 0.85*nmda); max of unscaled for ignition
      const float cA0 = __fmul_rn(nmA.x, C_WTA), cA1 = __fmul_rn(nmA.y, C_WTA);
      const float cA2 = __fmul_rn(nmA.z, C_WTA), cA3 = __fmul_rn(nmA.w, C_WTA);
      const float cB0 = __fmul_rn(nmB.x, C_WTA), cB1 = __fmul_rn(nmB.y, C_WTA);
      const float cB2 = __fmul_rn(nmB.z, C_WTA), cB3 = __fmul_rn(nmB.w, C_WTA);
      float mx = fmaxf(fmaxf(fmaxf(nmA.x, nmA.y), fmaxf(nmA.z, nmA.w)),
                       fmaxf(fmaxf(nmB.x, nmB.y), fmaxf(nmB.z, nmB.w)));

      // local stable top-2 over 8 values, ascending index order (lowest index wins ties)
      float a1 = cA0; int i1 = baseA;
      float a2 = -__builtin_inff(); int i2 = 0x7fffffff;
      LOCAL_TOP2(cA1, baseA + 1); LOCAL_TOP2(cA2, baseA + 2); LOCAL_TOP2(cA3, baseA + 3);
      LOCAL_TOP2(cB0, baseB);     LOCAL_TOP2(cB1, baseB + 1);
      LOCAL_TOP2(cB2, baseB + 2); LOCAL_TOP2(cB3, baseB + 3);

      // wave butterfly (64 lanes)
#pragma unroll
      for (int m = 1; m < 64; m <<= 1) {
        const float b1 = __shfl_xor(a1, m, 64); const int j1 = __shfl_xor(i1, m, 64);
        const float b2 = __shfl_xor(a2, m, 64); const int j2 = __shfl_xor(i2, m, 64);
        mx = fmaxf(mx, __shfl_xor(mx, m, 64));
        merge2(a1, i1, a2, i2, b1, j1, b2, j2);
      }
      if (lane == 0) { ws1[r][wv] = a1; wi1s[r][wv] = i1; ws2[r][wv] = a2; wi2s[r][wv] = i2; wmx[r][wv] = mx; }
    }
    __syncthreads();

    // ---------- pass B: cross-wave reduce, 2 waves x 8 rows (8-lane groups) ----------
    if (wv < 2) {
      const int row = wv * 8 + (lane >> 3);
      const int q = lane & 7;
      float a1 = ws1[row][q]; int i1 = wi1s[row][q];
      float a2 = ws2[row][q]; int i2 = wi2s[row][q];
      float gm = wmx[row][q];
#pragma unroll
      for (int m = 1; m < 8; m <<= 1) {
        const float b1 = __shfl_xor(a1, m, 64); const int j1 = __shfl_xor(i1, m, 64);
        const float b2 = __shfl_xor(a2, m, 64); const int j2 = __shfl_xor(i2, m, 64);
        gm = fmaxf(gm, __shfl_xor(gm, m, 64));
        merge2(a1, i1, a2, i2, b1, j1, b2, j2);
      }
      if ((lane & 7) == 0) {
        const int ig = (gm >= C_THR) ? 1 : 0;
        gj1[row] = ig ? i1 : -1;        // -1 sentinel: nothing matches -> zero row
        gj2[row] = ig ? i2 : -1;
        cov[tg + row] = ig ? covval : 0.0f;
      }
    }
    __syncthreads();

    // ---------- pass C: stream out 16 mask rows (2 nontemporal float4 stores each) ----------
#pragma unroll
    for (int r = 0; r < 16; ++r) {
      const int j1 = gj1[r], j2 = gj2[r];
      f32x4 v, u;
      v.x = (j1 == baseA     || j2 == baseA)     ? 1.0f : 0.0f;
      v.y = (j1 == baseA + 1 || j2 == baseA + 1) ? 1.0f : 0.0f;
      v.z = (j1 == baseA + 2 || j2 == baseA + 2) ? 1.0f : 0.0f;
      v.w = (j1 == baseA + 3 || j2 == baseA + 3) ? 1.0f : 0.0f;
      u.x = (j1 == baseB     || j2 == baseB)     ? 1.0f : 0.0f;
      u.y = (j1 == baseB + 1 || j2 == baseB + 1) ? 1.0f : 0.0f;
      u.z = (j1 == baseB + 2 || j2 == baseB + 2) ? 1.0f : 0.0f;
      u.w = (j1 == baseB + 3 || j2 == baseB + 3) ? 1.0f : 0.0f;
      __builtin_nontemporal_store(v, &mk4[(size_t)(tg + r) * N4 + tid]);
      __builtin_nontemporal_store(u, &mk4[(size_t)(tg + r) * N4 + tid + half]);
    }
    if (g + 16 < L) __syncthreads();   // protect LDS reuse across groups
  }
}

extern "C" void kernel_launch(void* const* d_in, const int* in_sizes, int n_in,
                              void* d_out, int out_size, void* d_ws, size_t ws_size,
                              hipStream_t stream) {
  const float* spikes = (const float*)d_in[0];
  const float* nmda0  = (const float*)d_in[1];
  const int N = in_sizes[1];
  const int T = in_sizes[0] / N;

  float* out  = (float*)d_out;
  float* mask = out;                               // [T, N]
  float* cov  = out + (size_t)T * N;               // [T]
  float* nmf  = cov + T;                           // [N]

  // boundary-state chunk length L = 1<<Ls; shrink boundary count if ws is small
  int Ls = 4;
  while (((size_t)(T >> Ls)) * (size_t)N * sizeof(float) > ws_size && Ls < 13) ++Ls;
  const int L = 1 << Ls;
  const int C = T >> Ls;
  float* bnd = (float*)d_ws;                       // [C, N]

  gw_phase1<<<N / NPB, 128, 0, stream>>>(spikes, nmda0, bnd, nmf, T, N, Ls);
  gw_phase2<<<C, 512, 0, stream>>>(spikes, bnd, mask, cov, T, N, L, 2.0f / (float)N);
}